// Round 9
// baseline (331.006 us; speedup 1.0000x reference)
//
#include <hip/hip_runtime.h>

using short8 = __attribute__((ext_vector_type(8))) short;
using f32x4  = __attribute__((ext_vector_type(4))) float;

static constexpr int N_NODES = 100000;
static constexpr int N_EDGES = 3200000;
static constexpr int IN_DIM  = 512;
static constexpr int OUT_DIM = 128;
static constexpr int NBINS   = (N_NODES + 255) / 256;  // 391 bins of 256 nodes
static constexpr int NB      = 1024;                   // binning blocks
static constexpr int CHUNK   = N_EDGES / NB;           // 3125 edges/block (exact)

__device__ __forceinline__ short f2bf(float f) {
  unsigned u = __builtin_bit_cast(unsigned, f);
  u = (u + 0x7FFFu + ((u >> 16) & 1u)) >> 16;  // RNE
  return (short)u;
}

// ---------------- W [512][128] f32  ->  WT [128][512] bf16 ----------------
__global__ __launch_bounds__(256) void cast_WT(const float* __restrict__ W,
                                               short* __restrict__ WT) {
  const int idx = blockIdx.x * 256 + threadIdx.x;  // 65536 total
  const int c = idx >> 9, k = idx & 511;
  WT[(size_t)c * 512 + k] = f2bf(W[(size_t)k * 128 + c]);
}

// ---------------- direct-from-global MFMA GEMM: xwb = (x@W)*dinv ----------
// No LDS, no barriers. Wave = 32 rows x 128 cols; A per-lane from HBM
// (read exactly once), B per-lane from L2-resident WT; depth-1 A prefetch.
__global__ __launch_bounds__(256) void gemm_direct(const float* __restrict__ x,
                                                   const short* __restrict__ WT,
                                                   const float* __restrict__ dinv,
                                                   unsigned short* __restrict__ xwb) {
  const int tid = threadIdx.x;
  const int w   = tid >> 6;
  const int l   = tid & 63;
  const int lr  = l & 15;   // A row / B col within fragment
  const int lk  = l >> 4;   // k-subchunk
  const int row0 = blockIdx.x * 128 + w * 32;

  const int ra = min(row0 + lr, N_NODES - 1);       // clamp; masked at write
  const int rb = min(row0 + 16 + lr, N_NODES - 1);
  const float* pa = &x[(size_t)ra * IN_DIM + lk * 8];
  const float* pb = &x[(size_t)rb * IN_DIM + lk * 8];
  const short* wbase = WT + (size_t)lr * 512 + lk * 8;

  f32x4 acc[2][8] = {};

  float4 a00 = *reinterpret_cast<const float4*>(pa);
  float4 a01 = *reinterpret_cast<const float4*>(pa + 4);
  float4 a10 = *reinterpret_cast<const float4*>(pb);
  float4 a11 = *reinterpret_cast<const float4*>(pb + 4);

#pragma unroll
  for (int ks = 0; ks < 16; ++ks) {
    float4 n00, n01, n10, n11;
    if (ks < 15) {  // prefetch next A chunk (base+imm addressing)
      const float* qa = pa + (ks + 1) * 32;
      const float* qb = pb + (ks + 1) * 32;
      n00 = *reinterpret_cast<const float4*>(qa);
      n01 = *reinterpret_cast<const float4*>(qa + 4);
      n10 = *reinterpret_cast<const float4*>(qb);
      n11 = *reinterpret_cast<const float4*>(qb + 4);
    }

    short8 bb[8];
#pragma unroll
    for (int cf = 0; cf < 8; ++cf)
      bb[cf] = *reinterpret_cast<const short8*>(wbase + (size_t)cf * 16 * 512 + ks * 32);

    short8 a0, a1;
    a0[0] = f2bf(a00.x); a0[1] = f2bf(a00.y); a0[2] = f2bf(a00.z); a0[3] = f2bf(a00.w);
    a0[4] = f2bf(a01.x); a0[5] = f2bf(a01.y); a0[6] = f2bf(a01.z); a0[7] = f2bf(a01.w);
    a1[0] = f2bf(a10.x); a1[1] = f2bf(a10.y); a1[2] = f2bf(a10.z); a1[3] = f2bf(a10.w);
    a1[4] = f2bf(a11.x); a1[5] = f2bf(a11.y); a1[6] = f2bf(a11.z); a1[7] = f2bf(a11.w);

#pragma unroll
    for (int cf = 0; cf < 8; ++cf) {
      acc[0][cf] = __builtin_amdgcn_mfma_f32_16x16x32_bf16(a0, bb[cf], acc[0][cf], 0, 0, 0);
      acc[1][cf] = __builtin_amdgcn_mfma_f32_16x16x32_bf16(a1, bb[cf], acc[1][cf], 0, 0, 0);
    }

    a00 = n00; a01 = n01; a10 = n10; a11 = n11;
  }

  // C/D: col = lane&15 (=lr), row = (lane>>4)*4 + j (=lk*4+j)
#pragma unroll
  for (int m = 0; m < 2; ++m) {
#pragma unroll
    for (int j = 0; j < 4; ++j) {
      const int row = row0 + m * 16 + lk * 4 + j;
      if (row < N_NODES) {
        const float sc = dinv[row];  // prescale: xwb = xw * dinv[row]
        unsigned short* o = &xwb[(size_t)row * OUT_DIM + lr];
#pragma unroll
        for (int cf = 0; cf < 8; ++cf)
          o[cf * 16] = (unsigned short)f2bf(acc[m][cf][j] * sc);
      }
    }
  }
}

// ========== atomic-free edge grouping: 2-level binning, LDS-only atomics ====

// A1: per-block LDS histogram of bin = col>>8
__global__ __launch_bounds__(256) void bin_count(const int* __restrict__ ecol,
                                                 int* __restrict__ blkhist) {
  __shared__ int hist[NBINS];
  const int blk = blockIdx.x, tid = threadIdx.x;
  for (int i = tid; i < NBINS; i += 256) hist[i] = 0;
  __syncthreads();
  const int e0 = blk * CHUNK, e1 = e0 + CHUNK;
  for (int e = e0 + tid; e < e1; e += 256) atomicAdd(&hist[ecol[e] >> 8], 1);
  __syncthreads();
  for (int i = tid; i < NBINS; i += 256) blkhist[(size_t)blk * NBINS + i] = hist[i];
}

// A2a: per-bin exclusive scan over the NB block partials (in place)
__global__ __launch_bounds__(1024) void scan_blkhist(int* __restrict__ blkhist,
                                                     int* __restrict__ bintot) {
  __shared__ int sh[NB];
  const int bin = blockIdx.x, t = threadIdx.x;
  const int v = blkhist[(size_t)t * NBINS + bin];
  sh[t] = v;
  __syncthreads();
  for (int d = 1; d < NB; d <<= 1) {
    const int tv = (t >= d) ? sh[t - d] : 0;
    __syncthreads();
    sh[t] += tv;
    __syncthreads();
  }
  blkhist[(size_t)t * NBINS + bin] = sh[t] - v;  // exclusive prefix over blocks
  if (t == NB - 1) bintot[bin] = sh[t];
}

// A2b: exclusive scan over bin totals
__global__ __launch_bounds__(512) void scan_bins(const int* __restrict__ bintot,
                                                 int* __restrict__ binbase) {
  __shared__ int sh[512];
  const int t = threadIdx.x;
  const int v = (t < NBINS) ? bintot[t] : 0;
  sh[t] = v;
  __syncthreads();
  for (int d = 1; d < 512; d <<= 1) {
    const int tv = (t >= d) ? sh[t - d] : 0;
    __syncthreads();
    sh[t] += tv;
    __syncthreads();
  }
  if (t < NBINS) binbase[t] = sh[t] - v;
  if (t == NBINS - 1) binbase[NBINS] = sh[t];
}

// A3: scatter packed (local_col<<24 | row) into bin-segmented benc
__global__ __launch_bounds__(256) void bin_scatter(const int* __restrict__ erow,
                                                   const int* __restrict__ ecol,
                                                   const int* __restrict__ blkhist,
                                                   const int* __restrict__ binbase,
                                                   unsigned* __restrict__ benc) {
  __shared__ int cur[NBINS];
  const int blk = blockIdx.x, tid = threadIdx.x;
  for (int i = tid; i < NBINS; i += 256)
    cur[i] = binbase[i] + blkhist[(size_t)blk * NBINS + i];
  __syncthreads();
  const int e0 = blk * CHUNK, e1 = e0 + CHUNK;
  for (int e = e0 + tid; e < e1; e += 256) {
    const int c = ecol[e];
    const unsigned enc = (unsigned)erow[e] | ((unsigned)(c & 255) << 24);
    const int p = atomicAdd(&cur[c >> 8], 1);
    benc[p] = enc;
  }
}

// B: per-bin CSR build — offs, dinv, brow (one block per 256-node bin)
__global__ __launch_bounds__(256) void bin_build(const unsigned* __restrict__ benc,
                                                 const int* __restrict__ binbase,
                                                 int* __restrict__ brow,
                                                 int* __restrict__ offs,
                                                 float* __restrict__ dinv) {
  __shared__ int hist[256];
  __shared__ int sh[256];
  __shared__ int cur[256];
  const int b = blockIdx.x, tid = threadIdx.x;
  const int e0 = binbase[b], e1 = binbase[b + 1];
  hist[tid] = 0;
  __syncthreads();
  for (int e = e0 + tid; e < e1; e += 256) atomicAdd(&hist[benc[e] >> 24], 1);
  __syncthreads();
  const int d0 = hist[tid];
  sh[tid] = d0;
  __syncthreads();
  for (int d = 1; d < 256; d <<= 1) {
    const int tv = (tid >= d) ? sh[tid - d] : 0;
    __syncthreads();
    sh[tid] += tv;
    __syncthreads();
  }
  const int myoff = e0 + sh[tid] - d0;  // global CSR offset for node (b<<8)+tid
  cur[tid] = myoff;
  const int node = (b << 8) + tid;
  if (node < N_NODES) {
    offs[node] = myoff;
    dinv[node] = rsqrtf((float)d0 + 1.0f);
  }
  if (b == NBINS - 1 && tid == 255) offs[N_NODES] = e1;
  __syncthreads();
  for (int e = e0 + tid; e < e1; e += 256) {
    const unsigned v = benc[e];
    const int p = atomicAdd(&cur[v >> 24], 1);
    brow[p] = (int)(v & 0x00FFFFFFu);
  }
}

// ---------------- gather: one wave per destination node (prescaled bf16) ---
__global__ __launch_bounds__(256) void gather_out(const unsigned short* __restrict__ xwb,
                                                  const float* __restrict__ dinv,
                                                  const int* __restrict__ offs,
                                                  const int* __restrict__ brow,
                                                  const float* __restrict__ bias,
                                                  float* __restrict__ out) {
  const int lane = threadIdx.x & 63;
  const int node = blockIdx.x * (blockDim.x >> 6) + (threadIdx.x >> 6);
  if (node >= N_NODES) return;
  const float di = dinv[node];
  const int c0 = lane * 2;

  auto ld2 = [&](int r) -> float2 {
    const unsigned v = *reinterpret_cast<const unsigned*>(&xwb[(size_t)r * OUT_DIM + c0]);
    float2 f;
    f.x = __builtin_bit_cast(float, v << 16);
    f.y = __builtin_bit_cast(float, v & 0xFFFF0000u);
    return f;
  };

  float2 acc = ld2(node);  // self-loop: di * scaled[node] = di^2 * xw[node]

  int e = offs[node];
  const int e1 = offs[node + 1];
  for (; e + 8 <= e1; e += 8) {
    const int r0 = brow[e],     r1 = brow[e + 1], r2 = brow[e + 2], r3 = brow[e + 3];
    const int r4 = brow[e + 4], r5 = brow[e + 5], r6 = brow[e + 6], r7 = brow[e + 7];
    const float2 v0 = ld2(r0), v1 = ld2(r1), v2 = ld2(r2), v3 = ld2(r3);
    const float2 v4 = ld2(r4), v5 = ld2(r5), v6 = ld2(r6), v7 = ld2(r7);
    acc.x += ((v0.x + v1.x) + (v2.x + v3.x)) + ((v4.x + v5.x) + (v6.x + v7.x));
    acc.y += ((v0.y + v1.y) + (v2.y + v3.y)) + ((v4.y + v5.y) + (v6.y + v7.y));
  }
  for (; e < e1; ++e) {
    const float2 v = ld2(brow[e]);
    acc.x += v.x;
    acc.y += v.y;
  }

  const float2 bb = *reinterpret_cast<const float2*>(&bias[c0]);
  float2 o;
  o.x = acc.x * di + bb.x;
  o.y = acc.y * di + bb.y;
  *reinterpret_cast<float2*>(&out[(size_t)node * OUT_DIM + c0]) = o;
}

extern "C" void kernel_launch(void* const* d_in, const int* in_sizes, int n_in,
                              void* d_out, int out_size, void* d_ws, size_t ws_size,
                              hipStream_t stream) {
  const float* x    = (const float*)d_in[0];
  const int*   eidx = (const int*)d_in[1];
  const float* W    = (const float*)d_in[2];
  const float* b    = (const float*)d_in[3];
  float* out = (float*)d_out;

  const int* erow = eidx;            // sources
  const int* ecol = eidx + N_EDGES;  // destinations

  char* ws = (char*)d_ws;
  size_t off = 0;
  auto alloc = [&](size_t bytes) -> void* {
    void* p = ws + off;
    off = (off + bytes + 255) & ~(size_t)255;
    return p;
  };
  unsigned short* xwb = (unsigned short*)alloc((size_t)N_NODES * OUT_DIM * sizeof(short)); // 25.6MB
  short* WT      = (short*)alloc((size_t)OUT_DIM * IN_DIM * sizeof(short));    // 128KB
  float* dinv    = (float*)alloc((size_t)N_NODES * sizeof(float));             // 400KB
  int*   offs    = (int*)alloc((size_t)(N_NODES + 1) * sizeof(int));           // 400KB
  int*   blkhist = (int*)alloc((size_t)NB * NBINS * sizeof(int));              // 1.6MB
  int*   bintot  = (int*)alloc((size_t)NBINS * sizeof(int));
  int*   binbase = (int*)alloc((size_t)(NBINS + 1) * sizeof(int));
  int*   brow    = (int*)alloc((size_t)N_EDGES * sizeof(int));                 // 12.8MB
  unsigned* benc = (unsigned*)alloc((size_t)N_EDGES * sizeof(unsigned));       // 12.8MB

  cast_WT<<<256, 256, 0, stream>>>(W, WT);

  bin_count<<<NB, 256, 0, stream>>>(ecol, blkhist);
  scan_blkhist<<<NBINS, NB, 0, stream>>>(blkhist, bintot);
  scan_bins<<<1, 512, 0, stream>>>(bintot, binbase);
  bin_scatter<<<NB, 256, 0, stream>>>(erow, ecol, blkhist, binbase, benc);
  bin_build<<<NBINS, 256, 0, stream>>>(benc, binbase, brow, offs, dinv);

  gemm_direct<<<(N_NODES + 127) / 128, 256, 0, stream>>>(x, WT, dinv, xwb);
  gather_out<<<(N_NODES + 3) / 4, 256, 0, stream>>>(xwb, dinv, offs, brow, b, out);
}

// Round 10
// 313.915 us; speedup vs baseline: 1.0544x; 1.0544x over previous
//
#include <hip/hip_runtime.h>

using short8 = __attribute__((ext_vector_type(8))) short;
using f32x4  = __attribute__((ext_vector_type(4))) float;

static constexpr int N_NODES = 100000;
static constexpr int N_EDGES = 3200000;
static constexpr int IN_DIM  = 512;
static constexpr int OUT_DIM = 128;
static constexpr int NBINS   = (N_NODES + 255) / 256;  // 391 bins of 256 nodes
static constexpr int NB      = 1024;                   // binning blocks
static constexpr int CHUNK   = N_EDGES / NB;           // 3125 edges/block (exact)

__device__ __forceinline__ short f2bf(float f) {
  unsigned u = __builtin_bit_cast(unsigned, f);
  u = (u + 0x7FFFu + ((u >> 16) & 1u)) >> 16;  // RNE
  return (short)u;
}

// ---- W [512][128] f32 -> k-blocked bf16: WTb[ks][c][lk][j]  (ks=k>>5) ----
// short index: ((ks*128 + c)*4 + lk)*8 + j   with k = ks*32 + lk*8 + j
__global__ __launch_bounds__(256) void cast_WT(const float* __restrict__ W,
                                               short* __restrict__ WTb) {
  const int idx = blockIdx.x * 256 + threadIdx.x;  // 65536 total
  const int k = idx >> 7, c = idx & 127;
  const int ks = k >> 5, lk = (k >> 3) & 3, j = k & 7;
  WTb[(size_t)((ks * 128 + c) * 4 + lk) * 8 + j] = f2bf(W[(size_t)k * 128 + c]);
}

// ---------------- direct-from-global MFMA GEMM: xwb = (x@W)*dinv ----------
// No LDS/barriers. Wave = 16 rows x 128 cols (8 cf). 6250 waves.
// A,B double-buffered in regs; all loads base+imm; VGPR-capped at 128.
__global__ __launch_bounds__(256, 4) void gemm_direct(const float* __restrict__ x,
                                                      const short* __restrict__ WTb,
                                                      const float* __restrict__ dinv,
                                                      unsigned short* __restrict__ xwb) {
  const int tid = threadIdx.x;
  const int w   = tid >> 6;
  const int l   = tid & 63;
  const int lr  = l & 15;   // A row within fragment / B col within cf
  const int lk  = l >> 4;   // k-subchunk
  const int row0 = blockIdx.x * 64 + w * 16;

  const int ra = min(row0 + lr, N_NODES - 1);  // clamp; masked at write
  const float* pa = &x[(size_t)ra * IN_DIM + lk * 8];
  const char*  wb = reinterpret_cast<const char*>(WTb) + lr * 64 + lk * 16;

  f32x4 acc[8] = {};

  auto loadA = [&](int ks, float4& f0, float4& f1) {
    const float* s = pa + ks * 32;
    f0 = *reinterpret_cast<const float4*>(s);
    f1 = *reinterpret_cast<const float4*>(s + 4);
  };
  auto loadB = [&](int ks, short8* bb) {
    const char* base = wb + ks * 8192;
#pragma unroll
    for (int cf = 0; cf < 8; ++cf)
      bb[cf] = *reinterpret_cast<const short8*>(base + cf * 1024);
  };
  auto cvtA = [&](const float4& f0, const float4& f1) -> short8 {
    short8 a;
    a[0] = f2bf(f0.x); a[1] = f2bf(f0.y); a[2] = f2bf(f0.z); a[3] = f2bf(f0.w);
    a[4] = f2bf(f1.x); a[5] = f2bf(f1.y); a[6] = f2bf(f1.z); a[7] = f2bf(f1.w);
    return a;
  };

  float4 cA0, cA1, nA0, nA1;
  short8 cB[8], nB[8];

  loadA(0, cA0, cA1);
  loadB(0, cB);

#pragma unroll
  for (int ks = 0; ks < 16; ++ks) {
    if (ks < 15) {           // issue next-ks loads before consuming cur
      loadA(ks + 1, nA0, nA1);
      loadB(ks + 1, nB);
    }
    const short8 a = cvtA(cA0, cA1);
#pragma unroll
    for (int cf = 0; cf < 8; ++cf)
      acc[cf] = __builtin_amdgcn_mfma_f32_16x16x32_bf16(a, cB[cf], acc[cf], 0, 0, 0);
    if (ks < 15) {
      cA0 = nA0; cA1 = nA1;
#pragma unroll
      for (int cf = 0; cf < 8; ++cf) cB[cf] = nB[cf];
    }
  }

  // C/D: col = lane&15 (=lr within cf), row = (lane>>4)*4 + j (=lk*4+j)
#pragma unroll
  for (int j = 0; j < 4; ++j) {
    const int row = row0 + lk * 4 + j;
    if (row < N_NODES) {
      const float sc = dinv[row];  // prescale: xwb = xw * dinv[row]
      unsigned short* o = &xwb[(size_t)row * OUT_DIM + lr];
#pragma unroll
      for (int cf = 0; cf < 8; ++cf)
        o[cf * 16] = (unsigned short)f2bf(acc[cf][j] * sc);
    }
  }
}

// ========== atomic-free edge grouping: 2-level binning, LDS-only atomics ====

// A1: per-block LDS histogram of bin = col>>8
__global__ __launch_bounds__(256) void bin_count(const int* __restrict__ ecol,
                                                 int* __restrict__ blkhist) {
  __shared__ int hist[NBINS];
  const int blk = blockIdx.x, tid = threadIdx.x;
  for (int i = tid; i < NBINS; i += 256) hist[i] = 0;
  __syncthreads();
  const int e0 = blk * CHUNK, e1 = e0 + CHUNK;
  for (int e = e0 + tid; e < e1; e += 256) atomicAdd(&hist[ecol[e] >> 8], 1);
  __syncthreads();
  for (int i = tid; i < NBINS; i += 256) blkhist[(size_t)blk * NBINS + i] = hist[i];
}

// A2a: per-bin exclusive scan over the NB block partials (in place)
__global__ __launch_bounds__(1024) void scan_blkhist(int* __restrict__ blkhist,
                                                     int* __restrict__ bintot) {
  __shared__ int sh[NB];
  const int bin = blockIdx.x, t = threadIdx.x;
  const int v = blkhist[(size_t)t * NBINS + bin];
  sh[t] = v;
  __syncthreads();
  for (int d = 1; d < NB; d <<= 1) {
    const int tv = (t >= d) ? sh[t - d] : 0;
    __syncthreads();
    sh[t] += tv;
    __syncthreads();
  }
  blkhist[(size_t)t * NBINS + bin] = sh[t] - v;  // exclusive prefix over blocks
  if (t == NB - 1) bintot[bin] = sh[t];
}

// A2b: exclusive scan over bin totals
__global__ __launch_bounds__(512) void scan_bins(const int* __restrict__ bintot,
                                                 int* __restrict__ binbase) {
  __shared__ int sh[512];
  const int t = threadIdx.x;
  const int v = (t < NBINS) ? bintot[t] : 0;
  sh[t] = v;
  __syncthreads();
  for (int d = 1; d < 512; d <<= 1) {
    const int tv = (t >= d) ? sh[t - d] : 0;
    __syncthreads();
    sh[t] += tv;
    __syncthreads();
  }
  if (t < NBINS) binbase[t] = sh[t] - v;
  if (t == NBINS - 1) binbase[NBINS] = sh[t];
}

// A3: scatter packed (local_col<<24 | row) into bin-segmented benc
__global__ __launch_bounds__(256) void bin_scatter(const int* __restrict__ erow,
                                                   const int* __restrict__ ecol,
                                                   const int* __restrict__ blkhist,
                                                   const int* __restrict__ binbase,
                                                   unsigned* __restrict__ benc) {
  __shared__ int cur[NBINS];
  const int blk = blockIdx.x, tid = threadIdx.x;
  for (int i = tid; i < NBINS; i += 256)
    cur[i] = binbase[i] + blkhist[(size_t)blk * NBINS + i];
  __syncthreads();
  const int e0 = blk * CHUNK, e1 = e0 + CHUNK;
  for (int e = e0 + tid; e < e1; e += 256) {
    const int c = ecol[e];
    const unsigned enc = (unsigned)erow[e] | ((unsigned)(c & 255) << 24);
    const int p = atomicAdd(&cur[c >> 8], 1);
    benc[p] = enc;
  }
}

// B: per-bin CSR build — offs, dinv, brow (one block per 256-node bin)
__global__ __launch_bounds__(256) void bin_build(const unsigned* __restrict__ benc,
                                                 const int* __restrict__ binbase,
                                                 int* __restrict__ brow,
                                                 int* __restrict__ offs,
                                                 float* __restrict__ dinv) {
  __shared__ int hist[256];
  __shared__ int sh[256];
  __shared__ int cur[256];
  const int b = blockIdx.x, tid = threadIdx.x;
  const int e0 = binbase[b], e1 = binbase[b + 1];
  hist[tid] = 0;
  __syncthreads();
  for (int e = e0 + tid; e < e1; e += 256) atomicAdd(&hist[benc[e] >> 24], 1);
  __syncthreads();
  const int d0 = hist[tid];
  sh[tid] = d0;
  __syncthreads();
  for (int d = 1; d < 256; d <<= 1) {
    const int tv = (tid >= d) ? sh[tid - d] : 0;
    __syncthreads();
    sh[tid] += tv;
    __syncthreads();
  }
  const int myoff = e0 + sh[tid] - d0;  // global CSR offset for node (b<<8)+tid
  cur[tid] = myoff;
  const int node = (b << 8) + tid;
  if (node < N_NODES) {
    offs[node] = myoff;
    dinv[node] = rsqrtf((float)d0 + 1.0f);
  }
  if (b == NBINS - 1 && tid == 255) offs[N_NODES] = e1;
  __syncthreads();
  for (int e = e0 + tid; e < e1; e += 256) {
    const unsigned v = benc[e];
    const int p = atomicAdd(&cur[v >> 24], 1);
    brow[p] = (int)(v & 0x00FFFFFFu);
  }
}

// ---------------- gather: one wave per destination node (prescaled bf16) ---
__global__ __launch_bounds__(256) void gather_out(const unsigned short* __restrict__ xwb,
                                                  const float* __restrict__ dinv,
                                                  const int* __restrict__ offs,
                                                  const int* __restrict__ brow,
                                                  const float* __restrict__ bias,
                                                  float* __restrict__ out) {
  const int lane = threadIdx.x & 63;
  const int node = blockIdx.x * (blockDim.x >> 6) + (threadIdx.x >> 6);
  if (node >= N_NODES) return;
  const float di = dinv[node];
  const int c0 = lane * 2;

  auto ld2 = [&](int r) -> float2 {
    const unsigned v = *reinterpret_cast<const unsigned*>(&xwb[(size_t)r * OUT_DIM + c0]);
    float2 f;
    f.x = __builtin_bit_cast(float, v << 16);
    f.y = __builtin_bit_cast(float, v & 0xFFFF0000u);
    return f;
  };

  float2 acc = ld2(node);  // self-loop: di * scaled[node] = di^2 * xw[node]

  int e = offs[node];
  const int e1 = offs[node + 1];
  for (; e + 8 <= e1; e += 8) {
    const int r0 = brow[e],     r1 = brow[e + 1], r2 = brow[e + 2], r3 = brow[e + 3];
    const int r4 = brow[e + 4], r5 = brow[e + 5], r6 = brow[e + 6], r7 = brow[e + 7];
    const float2 v0 = ld2(r0), v1 = ld2(r1), v2 = ld2(r2), v3 = ld2(r3);
    const float2 v4 = ld2(r4), v5 = ld2(r5), v6 = ld2(r6), v7 = ld2(r7);
    acc.x += ((v0.x + v1.x) + (v2.x + v3.x)) + ((v4.x + v5.x) + (v6.x + v7.x));
    acc.y += ((v0.y + v1.y) + (v2.y + v3.y)) + ((v4.y + v5.y) + (v6.y + v7.y));
  }
  for (; e < e1; ++e) {
    const float2 v = ld2(brow[e]);
    acc.x += v.x;
    acc.y += v.y;
  }

  const float2 bb = *reinterpret_cast<const float2*>(&bias[c0]);
  float2 o;
  o.x = acc.x * di + bb.x;
  o.y = acc.y * di + bb.y;
  *reinterpret_cast<float2*>(&out[(size_t)node * OUT_DIM + c0]) = o;
}

extern "C" void kernel_launch(void* const* d_in, const int* in_sizes, int n_in,
                              void* d_out, int out_size, void* d_ws, size_t ws_size,
                              hipStream_t stream) {
  const float* x    = (const float*)d_in[0];
  const int*   eidx = (const int*)d_in[1];
  const float* W    = (const float*)d_in[2];
  const float* b    = (const float*)d_in[3];
  float* out = (float*)d_out;

  const int* erow = eidx;            // sources
  const int* ecol = eidx + N_EDGES;  // destinations

  char* ws = (char*)d_ws;
  size_t off = 0;
  auto alloc = [&](size_t bytes) -> void* {
    void* p = ws + off;
    off = (off + bytes + 255) & ~(size_t)255;
    return p;
  };
  unsigned short* xwb = (unsigned short*)alloc((size_t)N_NODES * OUT_DIM * sizeof(short)); // 25.6MB
  short* WTb     = (short*)alloc((size_t)OUT_DIM * IN_DIM * sizeof(short));    // 128KB
  float* dinv    = (float*)alloc((size_t)N_NODES * sizeof(float));             // 400KB
  int*   offs    = (int*)alloc((size_t)(N_NODES + 1) * sizeof(int));           // 400KB
  int*   blkhist = (int*)alloc((size_t)NB * NBINS * sizeof(int));              // 1.6MB
  int*   bintot  = (int*)alloc((size_t)NBINS * sizeof(int));
  int*   binbase = (int*)alloc((size_t)(NBINS + 1) * sizeof(int));
  int*   brow    = (int*)alloc((size_t)N_EDGES * sizeof(int));                 // 12.8MB
  unsigned* benc = (unsigned*)alloc((size_t)N_EDGES * sizeof(unsigned));       // 12.8MB

  cast_WT<<<256, 256, 0, stream>>>(W, WTb);

  bin_count<<<NB, 256, 0, stream>>>(ecol, blkhist);
  scan_blkhist<<<NBINS, NB, 0, stream>>>(blkhist, bintot);
  scan_bins<<<1, 512, 0, stream>>>(bintot, binbase);
  bin_scatter<<<NB, 256, 0, stream>>>(erow, ecol, blkhist, binbase, benc);
  bin_build<<<NBINS, 256, 0, stream>>>(benc, binbase, brow, offs, dinv);

  gemm_direct<<<(N_NODES + 63) / 64, 256, 0, stream>>>(x, WTb, dinv, xwb);
  gather_out<<<(N_NODES + 3) / 4, 256, 0, stream>>>(xwb, dinv, offs, brow, b, out);
}

// Round 12
// 309.022 us; speedup vs baseline: 1.0711x; 1.0158x over previous
//
#include <hip/hip_runtime.h>

using short8  = __attribute__((ext_vector_type(8))) short;
using f32x4   = __attribute__((ext_vector_type(4))) float;
using uint32x4 = __attribute__((ext_vector_type(4))) unsigned;

static constexpr int N_NODES = 100000;
static constexpr int N_EDGES = 3200000;
static constexpr int IN_DIM  = 512;
static constexpr int OUT_DIM = 128;
static constexpr int NBINS   = (N_NODES + 255) / 256;  // 391 bins of 256 nodes
static constexpr int NB      = 1024;                   // binning blocks
static constexpr int CHUNK   = N_EDGES / NB;           // 3125 edges/block (exact)

__device__ __forceinline__ short f2bf(float f) {
  unsigned u = __builtin_bit_cast(unsigned, f);
  u = (u + 0x7FFFu + ((u >> 16) & 1u)) >> 16;  // RNE
  return (short)u;
}

// ---- W [512][128] f32 -> k-blocked bf16: WTb[ks][c][lk][j]  (ks=k>>5) ----
__global__ __launch_bounds__(256) void cast_WT(const float* __restrict__ W,
                                               short* __restrict__ WTb) {
  const int idx = blockIdx.x * 256 + threadIdx.x;  // 65536 total
  const int k = idx >> 7, c = idx & 127;
  const int ks = k >> 5, lk = (k >> 3) & 3, j = k & 7;
  WTb[(size_t)((ks * 128 + c) * 4 + lk) * 8 + j] = f2bf(W[(size_t)k * 128 + c]);
}

// ---------------- direct-from-global MFMA GEMM: xwb = (x@W)*dinv ----------
// No LDS/barriers. Wave = 16 rows x 128 cols. Copy-free ping-pong A/B regs,
// hw v_cvt_pk_bf16_f32 for f32->bf16, all loads base+imm.
__global__ __launch_bounds__(256, 4) void gemm_direct(const float* __restrict__ x,
                                                      const short* __restrict__ WTb,
                                                      const float* __restrict__ dinv,
                                                      unsigned short* __restrict__ xwb) {
  const int tid = threadIdx.x;
  const int w   = tid >> 6;
  const int l   = tid & 63;
  const int lr  = l & 15;   // A row within fragment / B col within cf
  const int lk  = l >> 4;   // k-subchunk
  const int row0 = blockIdx.x * 64 + w * 16;

  const int ra = min(row0 + lr, N_NODES - 1);  // clamp; masked at write
  const float* pa = &x[(size_t)ra * IN_DIM + lk * 8];
  const char*  wb = reinterpret_cast<const char*>(WTb) + lr * 64 + lk * 16;

  f32x4 acc[8] = {};

  float4 A0[2], A1[2];
  short8 B[2][8];

  auto loadA = [&](int ks, int s) {
    const float* p = pa + ks * 32;
    A0[s] = *reinterpret_cast<const float4*>(p);
    A1[s] = *reinterpret_cast<const float4*>(p + 4);
  };
  auto loadB = [&](int ks, int s) {
    const char* base = wb + ks * 8192;
#pragma unroll
    for (int cf = 0; cf < 8; ++cf)
      B[s][cf] = *reinterpret_cast<const short8*>(base + cf * 1024);
  };
  auto cvt2 = [](float lo, float hi) -> unsigned {
    unsigned r;
    asm("v_cvt_pk_bf16_f32 %0, %1, %2" : "=v"(r) : "v"(lo), "v"(hi));
    return r;
  };
  auto compute = [&](int s) {
    uint32x4 ua;
    ua[0] = cvt2(A0[s].x, A0[s].y);
    ua[1] = cvt2(A0[s].z, A0[s].w);
    ua[2] = cvt2(A1[s].x, A1[s].y);
    ua[3] = cvt2(A1[s].z, A1[s].w);
    const short8 a = __builtin_bit_cast(short8, ua);
#pragma unroll
    for (int cf = 0; cf < 8; ++cf)
      acc[cf] = __builtin_amdgcn_mfma_f32_16x16x32_bf16(a, B[s][cf], acc[cf], 0, 0, 0);
  };

  loadA(0, 0);
  loadB(0, 0);

#pragma unroll
  for (int kp = 0; kp < 8; ++kp) {
    const int ks = kp * 2;
    // set1 <- ks+1 while computing set0 (ks)
    loadA(ks + 1, 1);
    loadB(ks + 1, 1);
    compute(0);
    // set0 <- ks+2 while computing set1 (ks+1)
    if (kp < 7) {
      loadA(ks + 2, 0);
      loadB(ks + 2, 0);
    }
    compute(1);
  }

  // C/D: col = lane&15 (=lr within cf), row = (lane>>4)*4 + j (=lk*4+j)
#pragma unroll
  for (int j = 0; j < 4; ++j) {
    const int row = row0 + lk * 4 + j;
    if (row < N_NODES) {
      const float sc = dinv[row];  // prescale: xwb = xw * dinv[row]
      unsigned short* o = &xwb[(size_t)row * OUT_DIM + lr];
#pragma unroll
      for (int cf = 0; cf < 8; ++cf)
        o[cf * 16] = (unsigned short)f2bf(acc[cf][j] * sc);
    }
  }
}

// ========== atomic-free edge grouping: 2-level binning, LDS-only atomics ====

// A1: per-block LDS histogram of bin = col>>8
__global__ __launch_bounds__(256) void bin_count(const int* __restrict__ ecol,
                                                 int* __restrict__ blkhist) {
  __shared__ int hist[NBINS];
  const int blk = blockIdx.x, tid = threadIdx.x;
  for (int i = tid; i < NBINS; i += 256) hist[i] = 0;
  __syncthreads();
  const int e0 = blk * CHUNK, e1 = e0 + CHUNK;
  for (int e = e0 + tid; e < e1; e += 256) atomicAdd(&hist[ecol[e] >> 8], 1);
  __syncthreads();
  for (int i = tid; i < NBINS; i += 256) blkhist[(size_t)blk * NBINS + i] = hist[i];
}

// A2a: per-bin exclusive scan over the NB block partials (in place)
__global__ __launch_bounds__(1024) void scan_blkhist(int* __restrict__ blkhist,
                                                     int* __restrict__ bintot) {
  __shared__ int sh[NB];
  const int bin = blockIdx.x, t = threadIdx.x;
  const int v = blkhist[(size_t)t * NBINS + bin];
  sh[t] = v;
  __syncthreads();
  for (int d = 1; d < NB; d <<= 1) {
    const int tv = (t >= d) ? sh[t - d] : 0;
    __syncthreads();
    sh[t] += tv;
    __syncthreads();
  }
  blkhist[(size_t)t * NBINS + bin] = sh[t] - v;  // exclusive prefix over blocks
  if (t == NB - 1) bintot[bin] = sh[t];
}

// A2b: exclusive scan over bin totals
__global__ __launch_bounds__(512) void scan_bins(const int* __restrict__ bintot,
                                                 int* __restrict__ binbase) {
  __shared__ int sh[512];
  const int t = threadIdx.x;
  const int v = (t < NBINS) ? bintot[t] : 0;
  sh[t] = v;
  __syncthreads();
  for (int d = 1; d < 512; d <<= 1) {
    const int tv = (t >= d) ? sh[t - d] : 0;
    __syncthreads();
    sh[t] += tv;
    __syncthreads();
  }
  if (t < NBINS) binbase[t] = sh[t] - v;
  if (t == NBINS - 1) binbase[NBINS] = sh[t];
}

// A3: scatter packed (local_col<<24 | row) into bin-segmented benc
__global__ __launch_bounds__(256) void bin_scatter(const int* __restrict__ erow,
                                                   const int* __restrict__ ecol,
                                                   const int* __restrict__ blkhist,
                                                   const int* __restrict__ binbase,
                                                   unsigned* __restrict__ benc) {
  __shared__ int cur[NBINS];
  const int blk = blockIdx.x, tid = threadIdx.x;
  for (int i = tid; i < NBINS; i += 256)
    cur[i] = binbase[i] + blkhist[(size_t)blk * NBINS + i];
  __syncthreads();
  const int e0 = blk * CHUNK, e1 = e0 + CHUNK;
  for (int e = e0 + tid; e < e1; e += 256) {
    const int c = ecol[e];
    const unsigned enc = (unsigned)erow[e] | ((unsigned)(c & 255) << 24);
    const int p = atomicAdd(&cur[c >> 8], 1);
    benc[p] = enc;
  }
}

// B: per-bin CSR build — offs, dinv, brow (one block per 256-node bin)
__global__ __launch_bounds__(256) void bin_build(const unsigned* __restrict__ benc,
                                                 const int* __restrict__ binbase,
                                                 int* __restrict__ brow,
                                                 int* __restrict__ offs,
                                                 float* __restrict__ dinv) {
  __shared__ int hist[256];
  __shared__ int sh[256];
  __shared__ int cur[256];
  const int b = blockIdx.x, tid = threadIdx.x;
  const int e0 = binbase[b], e1 = binbase[b + 1];
  hist[tid] = 0;
  __syncthreads();
  for (int e = e0 + tid; e < e1; e += 256) atomicAdd(&hist[benc[e] >> 24], 1);
  __syncthreads();
  const int d0 = hist[tid];
  sh[tid] = d0;
  __syncthreads();
  for (int d = 1; d < 256; d <<= 1) {
    const int tv = (tid >= d) ? sh[tid - d] : 0;
    __syncthreads();
    sh[tid] += tv;
    __syncthreads();
  }
  const int myoff = e0 + sh[tid] - d0;  // global CSR offset for node (b<<8)+tid
  cur[tid] = myoff;
  const int node = (b << 8) + tid;
  if (node < N_NODES) {
    offs[node] = myoff;
    dinv[node] = rsqrtf((float)d0 + 1.0f);
  }
  if (b == NBINS - 1 && tid == 255) offs[N_NODES] = e1;
  __syncthreads();
  for (int e = e0 + tid; e < e1; e += 256) {
    const unsigned v = benc[e];
    const int p = atomicAdd(&cur[v >> 24], 1);
    brow[p] = (int)(v & 0x00FFFFFFu);
  }
}

// ---------------- gather: one wave per destination node (prescaled bf16) ---
__global__ __launch_bounds__(256) void gather_out(const unsigned short* __restrict__ xwb,
                                                  const float* __restrict__ dinv,
                                                  const int* __restrict__ offs,
                                                  const int* __restrict__ brow,
                                                  const float* __restrict__ bias,
                                                  float* __restrict__ out) {
  const int lane = threadIdx.x & 63;
  const int node = blockIdx.x * (blockDim.x >> 6) + (threadIdx.x >> 6);
  if (node >= N_NODES) return;
  const float di = dinv[node];
  const int c0 = lane * 2;

  auto ld2 = [&](int r) -> float2 {
    const unsigned v = *reinterpret_cast<const unsigned*>(&xwb[(size_t)r * OUT_DIM + c0]);
    float2 f;
    f.x = __builtin_bit_cast(float, v << 16);
    f.y = __builtin_bit_cast(float, v & 0xFFFF0000u);
    return f;
  };

  float2 acc = ld2(node);  // self-loop: di * scaled[node] = di^2 * xw[node]

  int e = offs[node];
  const int e1 = offs[node + 1];
  for (; e + 8 <= e1; e += 8) {
    const int r0 = brow[e],     r1 = brow[e + 1], r2 = brow[e + 2], r3 = brow[e + 3];
    const int r4 = brow[e + 4], r5 = brow[e + 5], r6 = brow[e + 6], r7 = brow[e + 7];
    const float2 v0 = ld2(r0), v1 = ld2(r1), v2 = ld2(r2), v3 = ld2(r3);
    const float2 v4 = ld2(r4), v5 = ld2(r5), v6 = ld2(r6), v7 = ld2(r7);
    acc.x += ((v0.x + v1.x) + (v2.x + v3.x)) + ((v4.x + v5.x) + (v6.x + v7.x));
    acc.y += ((v0.y + v1.y) + (v2.y + v3.y)) + ((v4.y + v5.y) + (v6.y + v7.y));
  }
  for (; e < e1; ++e) {
    const float2 v = ld2(brow[e]);
    acc.x += v.x;
    acc.y += v.y;
  }

  const float2 bb = *reinterpret_cast<const float2*>(&bias[c0]);
  float2 o;
  o.x = acc.x * di + bb.x;
  o.y = acc.y * di + bb.y;
  *reinterpret_cast<float2*>(&out[(size_t)node * OUT_DIM + c0]) = o;
}

extern "C" void kernel_launch(void* const* d_in, const int* in_sizes, int n_in,
                              void* d_out, int out_size, void* d_ws, size_t ws_size,
                              hipStream_t stream) {
  const float* x    = (const float*)d_in[0];
  const int*   eidx = (const int*)d_in[1];
  const float* W    = (const float*)d_in[2];
  const float* b    = (const float*)d_in[3];
  float* out = (float*)d_out;

  const int* erow = eidx;            // sources
  const int* ecol = eidx + N_EDGES;  // destinations

  char* ws = (char*)d_ws;
  size_t off = 0;
  auto alloc = [&](size_t bytes) -> void* {
    void* p = ws + off;
    off = (off + bytes + 255) & ~(size_t)255;
    return p;
  };
  unsigned short* xwb = (unsigned short*)alloc((size_t)N_NODES * OUT_DIM * sizeof(short)); // 25.6MB
  short* WTb     = (short*)alloc((size_t)OUT_DIM * IN_DIM * sizeof(short));    // 128KB
  float* dinv    = (float*)alloc((size_t)N_NODES * sizeof(float));             // 400KB
  int*   offs    = (int*)alloc((size_t)(N_NODES + 1) * sizeof(int));           // 400KB
  int*   blkhist = (int*)alloc((size_t)NB * NBINS * sizeof(int));              // 1.6MB
  int*   bintot  = (int*)alloc((size_t)NBINS * sizeof(int));
  int*   binbase = (int*)alloc((size_t)(NBINS + 1) * sizeof(int));
  int*   brow    = (int*)alloc((size_t)N_EDGES * sizeof(int));                 // 12.8MB
  unsigned* benc = (unsigned*)alloc((size_t)N_EDGES * sizeof(unsigned));       // 12.8MB

  cast_WT<<<256, 256, 0, stream>>>(W, WTb);

  bin_count<<<NB, 256, 0, stream>>>(ecol, blkhist);
  scan_blkhist<<<NBINS, NB, 0, stream>>>(blkhist, bintot);
  scan_bins<<<1, 512, 0, stream>>>(bintot, binbase);
  bin_scatter<<<NB, 256, 0, stream>>>(erow, ecol, blkhist, binbase, benc);
  bin_build<<<NBINS, 256, 0, stream>>>(benc, binbase, brow, offs, dinv);

  gemm_direct<<<(N_NODES + 63) / 64, 256, 0, stream>>>(x, WTb, dinv, xwb);
  gather_out<<<(N_NODES + 3) / 4, 256, 0, stream>>>(xwb, dinv, offs, brow, b, out);
}